// Round 4
// baseline (521.566 us; speedup 1.0000x reference)
//
#include <hip/hip_runtime.h>
#include <hip/hip_bf16.h>

// Problem dims (fixed)
#define B_   4
#define C1_  512
#define T_   256
#define H_   64
#define TH_  (T_*H_)     // 16384
#define AUX_ 256
#define OUT_ 512
#define INF_ 768         // C1+AUX
#define BK   32
#define THB  64
#define NKS  (C1_/BK)    // 16 K-steps

typedef __attribute__((ext_vector_type(8))) short bf16x8;
typedef __attribute__((ext_vector_type(4))) float f32x4;
typedef __attribute__((address_space(3))) void* lds_vp;
typedef const __attribute__((address_space(1))) void* gbl_vp;

__device__ __forceinline__ ushort bf16u(float f) {
    __hip_bfloat16 h = __float2bfloat16(f);
    return *reinterpret_cast<ushort*>(&h);
}

// prep1: W[:, :512] fp32 -> bf16 (Wbf[o][c], contiguous 512)
__global__ void wconv_kernel(const float* __restrict__ W, ushort* __restrict__ Wbf) {
    int idx = (blockIdx.x * 256 + threadIdx.x) * 4;
    int o = idx >> 9, c = idx & 511;
    const float4 v = *(const float4*)(W + (size_t)o * INF_ + c);
    ushort4 u = make_ushort4(bf16u(v.x), bf16u(v.y), bf16u(v.z), bf16u(v.w));
    *(ushort4*)(Wbf + idx) = u;
}

// prep2: sW[b][o] = bias[o] + sum_c s[b][c] * W[o][512+c]
__global__ void sw_kernel(const float* __restrict__ s, const float* __restrict__ W,
                          const float* __restrict__ bias, float* __restrict__ sW) {
    __shared__ float sl[AUX_];
    int b = blockIdx.x, o = threadIdx.x;
    for (int c = threadIdx.x; c < AUX_; c += 512) sl[c] = s[b * AUX_ + c];
    __syncthreads();
    float acc = bias[o];
    const float* wr = W + (size_t)o * INF_ + C1_;
    #pragma unroll 8
    for (int c = 0; c < AUX_; c += 4) {
        float4 w = *(const float4*)(wr + c);
        acc += sl[c] * w.x + sl[c+1] * w.y + sl[c+2] * w.z + sl[c+3] * w.w;
    }
    sW[b * OUT_ + o] = acc;
}

// main fused kernel: GEMM(512 x THB, K=512) + sW-bias + PReLU + LayerNorm(o) + residual
// 2-phase pipeline: double-buffered LDS, global_load_lds W staging (source
// pre-swizzled so reads are conflict-free), reg-staged X transpose, 1 barrier/step.
// LDS tile layout: [row][4 slots of 8 bf16]; LDS slot s holds global chunk
// s ^ ((row>>1)&3)  (involution; reader applies the same XOR).
__global__ __launch_bounds__(512, 4) void fused_kernel(
    const float* __restrict__ X, const ushort* __restrict__ Wbf,
    const float* __restrict__ sW, const float* __restrict__ a2p,
    const float* __restrict__ ln2w, const float* __restrict__ ln2b,
    float* __restrict__ Yout)
{
    __shared__ __align__(16) ushort Ws[2][C1_ * BK];   // 2 x 32 KB, linear (gload_lds dest)
    __shared__ __align__(16) ushort Xs[2][THB * BK];   // 2 x 4 KB, swizzled writes
    __shared__ float red[8][THB][2];                   // 4 KB

    const int tid  = threadIdx.x;
    const int lane = tid & 63;
    const int w    = tid >> 6;
    const int b    = blockIdx.y;
    const int th0  = blockIdx.x * THB;
    const float* xb = X + (size_t)b * C1_ * TH_;
    const int l15 = lane & 15;
    const int lhi = lane >> 4;

    // X-staging role: threads 0..255, one column each, 8 channels per step
    const int xcol = tid & 63;
    const int xg   = tid >> 6;        // 0..3 for tid<256
    float xr[8];

    f32x4 acc[4][4] = {};

    // ---- staging helpers ----
    // W: 4 global_load_lds_dwordx4 issues per thread; LDS dest linear in tid,
    // global source pre-swizzled: lds (row,slot) <- global chunk slot^((row>>1)&3)
    auto stage_w = [&](int buf, int kc) {
        #pragma unroll
        for (int i = 0; i < 4; ++i) {
            int row  = i * 128 + (tid >> 2);
            int slot = tid & 3;
            int cch  = slot ^ ((row >> 1) & 3);
            const ushort* g = Wbf + (size_t)row * C1_ + kc + cch * 8;
            __builtin_amdgcn_global_load_lds((gbl_vp)g,
                (lds_vp)&Ws[buf][i * 4096 + tid * 8], 16, 0, 0);
        }
    };
    auto xload = [&](int kc) {
        if (tid < 256) {
            #pragma unroll
            for (int j = 0; j < 8; ++j)
                xr[j] = xb[(size_t)(kc + xg * 8 + j) * TH_ + th0 + xcol];
        }
    };
    auto xwrite = [&](int buf) {
        if (tid < 256) {
            int slot = xg ^ ((xcol >> 1) & 3);
            bf16x8 v;
            #pragma unroll
            for (int j = 0; j < 8; ++j) v[j] = (short)bf16u(xr[j]);
            *(bf16x8*)&Xs[buf][xcol * BK + slot * 8] = v;
        }
    };

    // ---- prologue: fill buffer 0 ----
    stage_w(0, 0);
    xload(0);
    xwrite(0);
    __syncthreads();   // drains vmcnt (gload_lds) + lgkm (ds_write)

    // ---- main loop: 1 barrier per K-step ----
    for (int kk = 0; kk < NKS; ++kk) {
        const int cur = kk & 1;
        if (kk + 1 < NKS) {
            stage_w(cur ^ 1, (kk + 1) * BK);   // prefetch W -> LDS (async)
            xload((kk + 1) * BK);              // prefetch X -> regs
        }
        // fragments from current buffer (swizzled reads, conflict-free)
        bf16x8 af[4], bfr[4];
        #pragma unroll
        for (int fm = 0; fm < 4; ++fm) {
            int row  = w * 64 + fm * 16 + l15;
            int slot = lhi ^ ((row >> 1) & 3);
            af[fm] = *(const bf16x8*)&Ws[cur][row * BK + slot * 8];
        }
        #pragma unroll
        for (int fn = 0; fn < 4; ++fn) {
            int row  = fn * 16 + l15;
            int slot = lhi ^ ((row >> 1) & 3);
            bfr[fn] = *(const bf16x8*)&Xs[cur][row * BK + slot * 8];
        }
        #pragma unroll
        for (int fm = 0; fm < 4; ++fm)
            #pragma unroll
            for (int fn = 0; fn < 4; ++fn)
                acc[fm][fn] = __builtin_amdgcn_mfma_f32_16x16x32_bf16(
                    af[fm], bfr[fn], acc[fm][fn], 0, 0, 0);
        if (kk + 1 < NKS) xwrite(cur ^ 1);     // convert + publish next X tile
        __syncthreads();
    }

    // ---- epilogue: +sW, PReLU, LN stats ----
    const float a2 = a2p[0];
    const int obase = w * 64;
    float swv[4][4];
    #pragma unroll
    for (int fm = 0; fm < 4; ++fm)
        #pragma unroll
        for (int r = 0; r < 4; ++r)
            swv[fm][r] = sW[b * OUT_ + obase + fm * 16 + lhi * 4 + r];

    float s1[4] = {0,0,0,0}, s2[4] = {0,0,0,0};
    #pragma unroll
    for (int fm = 0; fm < 4; ++fm) {
        #pragma unroll
        for (int fn = 0; fn < 4; ++fn) {
            #pragma unroll
            for (int r = 0; r < 4; ++r) {
                float z = acc[fm][fn][r] + swv[fm][r];
                float v = z >= 0.f ? z : a2 * z;
                acc[fm][fn][r] = v;
                s1[fn] += v; s2[fn] += v * v;
            }
        }
    }
    #pragma unroll
    for (int fn = 0; fn < 4; ++fn) {
        s1[fn] += __shfl_xor(s1[fn], 16, 64);
        s2[fn] += __shfl_xor(s2[fn], 16, 64);
        s1[fn] += __shfl_xor(s1[fn], 32, 64);
        s2[fn] += __shfl_xor(s2[fn], 32, 64);
    }
    if (lane < 16) {
        #pragma unroll
        for (int fn = 0; fn < 4; ++fn) {
            red[w][fn * 16 + lane][0] = s1[fn];
            red[w][fn * 16 + lane][1] = s2[fn];
        }
    }
    __syncthreads();
    float mean[4], rstd[4];
    #pragma unroll
    for (int fn = 0; fn < 4; ++fn) {
        float t1 = 0.f, t2 = 0.f;
        #pragma unroll
        for (int ww = 0; ww < 8; ++ww) {
            t1 += red[ww][fn * 16 + l15][0];
            t2 += red[ww][fn * 16 + l15][1];
        }
        float mu = t1 * (1.0f / OUT_);
        mean[fn] = mu;
        float var = t2 * (1.0f / OUT_) - mu * mu;
        rstd[fn] = rsqrtf(var + 1e-8f);
    }
    // ---- output: residual + LN affine ----
    #pragma unroll
    for (int fm = 0; fm < 4; ++fm) {
        #pragma unroll
        for (int r = 0; r < 4; ++r) {
            int o = obase + fm * 16 + lhi * 4 + r;
            float wo = ln2w[o], bo = ln2b[o];
            const float* xrow = xb + (size_t)o * TH_ + th0;
            float* yrow = Yout + ((size_t)b * OUT_ + o) * TH_ + th0;
            #pragma unroll
            for (int fn = 0; fn < 4; ++fn) {
                int col = fn * 16 + l15;
                float resid = xrow[col];
                yrow[col] = resid + (acc[fm][fn][r] - mean[fn]) * rstd[fn] * wo + bo;
            }
        }
    }
}

extern "C" void kernel_launch(void* const* d_in, const int* in_sizes, int n_in,
                              void* d_out, int out_size, void* d_ws, size_t ws_size,
                              hipStream_t stream) {
    const float* x    = (const float*)d_in[0];
    const float* s    = (const float*)d_in[1];
    const float* W    = (const float*)d_in[5];
    const float* bias = (const float*)d_in[6];
    const float* a2   = (const float*)d_in[7];
    const float* ln2w = (const float*)d_in[8];
    const float* ln2b = (const float*)d_in[9];
    float* out = (float*)d_out;

    ushort* Wbf = (ushort*)d_ws;                           // 512 KB
    float*  sW  = (float*)((char*)d_ws + C1_ * OUT_ * 2);  // 8 KB

    wconv_kernel<<<256, 256, 0, stream>>>(W, Wbf);
    sw_kernel<<<B_, 512, 0, stream>>>(s, W, bias, sW);
    dim3 grid(TH_ / THB, B_);
    fused_kernel<<<grid, 512, 0, stream>>>(x, Wbf, sW, a2, ln2w, ln2b, out);
}